// Round 6
// baseline (411.846 us; speedup 1.0000x reference)
//
#include <hip/hip_runtime.h>

// HMM scaled forward — fused decode + register-resident MFMA recurrence.
//   BATCH=128, T=8192, N_STATES=128, EMIT=64
// Each WG (bg, chunk) ballot-decodes its own 160 KB one-hot slice (16 lanes
// cover one 64-float row; 3 ballots encode the argmax; lane 0 writes 4 obs
// bytes/pass to LDS), then runs the chunk: permuted-K A fragments make the
// packed MFMA D-output directly the next step's B-fragment — alpha never
// leaves registers; no barrier in the loop. Normalization telescoped
// (B-table pre-scaled by 64): 2-3 shfl reductions per chunk total.

#define BATCH 128
#define TLEN 8192
#define NS 128
#define EMIT 64
#define NCHUNK 256
#define CLEN (TLEN / NCHUNK)   // 32
#define WARM 8
#define BG 8                   // batch groups of 16
#define BSTR 132               // B-table row stride (bf16 elems)
#define OSTR 48                // obs_l row stride (bytes, 16B-aligned)
#define LN64 4.158883083359672f

typedef __attribute__((ext_vector_type(8))) short short8;
typedef __attribute__((ext_vector_type(4))) float floatx4;
typedef __attribute__((ext_vector_type(4))) unsigned int uintx4;

__device__ __forceinline__ unsigned f2bf(float f) {
    return (__float_as_uint(f) + 0x8000u) >> 16;   // round-half-up to bf16
}

__global__ void zero_ll(float* __restrict__ out_ll) {
    out_ll[threadIdx.x] = 0.f;
}

__global__ __launch_bounds__(64) void hmm_scan(
        const floatx4* __restrict__ x,    // one-hot [B][T][EMIT] as float4s
        const float* __restrict__ Amat,
        const float* __restrict__ Bmat,
        const float* __restrict__ Ivec,
        float* __restrict__ out_alpha,    // [BATCH][NS]
        float* __restrict__ out_ll)       // [BATCH]
{
    __shared__ unsigned short Bl[EMIT * BSTR];    // 16896 B: bf16(64*B)
    __shared__ unsigned char obs_l[16 * OSTR];    // decoded obs bytes

    const int lane = threadIdx.x;
    const int n = lane & 15;              // batch within group (D col)
    const int q = lane >> 4;              // quad
    const int bg = blockIdx.x >> 8;       // / NCHUNK
    const int c = blockIdx.x & (NCHUNK - 1);
    const bool first = (c == 0);
    const bool lastc = (c == NCHUNK - 1);
    const int steps = first ? CLEN : (CLEN + WARM);
    const int t0 = first ? 0 : c * CLEN - WARM;

    // stage B scaled by 64 (exact pow2) as bf16, padded stride
    for (int i = lane; i < EMIT * NS; i += 64) {
        int e = i >> 7, col = i & (NS - 1);
        Bl[e * BSTR + col] = (unsigned short)f2bf(64.0f * Bmat[i]);
    }

    // ---- fused decode: this WG's one-hot slice -> obs_l[16][OSTR] ----
    // 16 lanes cover one (b,t) row: lane reads float4 #jj of the 64-float
    // row; 3 ballots recover the one-hot index wave-uniformly.
    {
        const int p_local = lane >> 4;    // which of 4 consecutive t
        const int jj = lane & 15;         // float4 within the row
        for (int bl = 0; bl < 16; ++bl) {
            const floatx4* bp = x + (((bg * 16 + bl) * TLEN + t0 + p_local) << 4) + jj;
            floatx4 vv[10];
            #pragma unroll
            for (int tg = 0; tg < 10; ++tg) vv[tg] = bp[tg * 64];   // t += 4
            #pragma unroll
            for (int tg = 0; tg < 10; ++tg) {
                floatx4 v = vv[tg];
                bool found = (v.x > 0.5f) || (v.y > 0.5f) || (v.z > 0.5f) || (v.w > 0.5f);
                bool e1 = (v.y > 0.5f) || (v.w > 0.5f);
                bool e2 = (v.z > 0.5f) || (v.w > 0.5f);
                unsigned long long m1 = __ballot(found);
                unsigned long long m2 = __ballot(e1);
                unsigned long long m3 = __ballot(e2);
                unsigned packed = 0;
                #pragma unroll
                for (int p = 0; p < 4; ++p) {
                    unsigned g = (unsigned)(m1 >> (16 * p)) & 0xFFFFu;
                    int j16 = __builtin_ctz(g);
                    int bit = 16 * p + j16;
                    unsigned e = (unsigned)((m2 >> bit) & 1ull) |
                                 ((unsigned)((m3 >> bit) & 1ull) << 1);
                    packed |= (unsigned)(j16 * 4 + e) << (8 * p);
                }
                if (lane == 0)
                    *(unsigned*)(obs_l + bl * OSTR + tg * 4) = packed;
            }
        }
    }

    // A fragments with permuted K-order so packed D == next B-frag.
    // position u = 32kf + 8q + j  ->  state 32(u>>5)+16((u>>2)&1)+4((u>>3)&3)+(u&3)
    short8 af[8][4];
    #pragma unroll
    for (int mt = 0; mt < 8; ++mt)
        #pragma unroll
        for (int kf = 0; kf < 4; ++kf) {
            short8 v;
            #pragma unroll
            for (int j = 0; j < 8; ++j) {
                int u = 32 * kf + 8 * q + j;
                int sk = 32 * (u >> 5) + 16 * ((u >> 2) & 1)
                       + 4 * ((u >> 3) & 3) + (u & 3);
                v[j] = (short)f2bf(Amat[sk * NS + 16 * mt + n]);
            }
            af[mt][kf] = v;
        }
    __syncthreads();   // Bl + obs_l ready

    // this lane's obs stream (row n) -> 10 dwords in registers
    unsigned ow[10];
    {
        uintx4 wa = *(const uintx4*)(obs_l + n * OSTR);
        uintx4 wb = *(const uintx4*)(obs_l + n * OSTR + 16);
        uint2  wc = *(const uint2*)(obs_l + n * OSTR + 32);
        ow[0] = wa.x; ow[1] = wa.y; ow[2] = wa.z; ow[3] = wa.w;
        ow[4] = wb.x; ow[5] = wb.y; ow[6] = wb.z; ow[7] = wb.w;
        ow[8] = wc.x; ow[9] = wc.y;
    }

    // loop-carried packed alpha (bf16 pairs); init uniform for warmup
    unsigned pk[16];
    #pragma unroll
    for (int i = 0; i < 16; ++i) pk[i] = 0x3C003C00u;   // bf16(1/128) x2

    float s_pre = 1.0f, s_penult = 1.0f, s_end = 1.0f;

    for (int it = 0; it < steps; ++it) {
        floatx4 acc[8];
        if (first && it == 0) {
            // t==0: R := I (exact init), alpha0 = 64B[o] * I
            #pragma unroll
            for (int mt = 0; mt < 8; ++mt)
                acc[mt] = *(const floatx4*)(Ivec + 16 * mt + 4 * q);
        } else {
            short8 bf[4];
            #pragma unroll
            for (int kf = 0; kf < 4; ++kf) {
                uintx4 u4 = {pk[4 * kf], pk[4 * kf + 1], pk[4 * kf + 2], pk[4 * kf + 3]};
                bf[kf] = __builtin_bit_cast(short8, u4);
            }
            #pragma unroll
            for (int mt = 0; mt < 8; ++mt) {
                floatx4 a = {0.f, 0.f, 0.f, 0.f};
                #pragma unroll
                for (int kf = 0; kf < 4; ++kf)
                    a = __builtin_amdgcn_mfma_f32_16x16x32_bf16(af[mt][kf], bf[kf], a, 0, 0, 0);
                acc[mt] = a;
            }
        }

        // emission multiply (table holds 64*B)
        int o = (ow[it >> 2] >> ((it & 3) * 8)) & 0xFF;
        int eb = o * BSTR;
        #pragma unroll
        for (int mt = 0; mt < 8; ++mt) {
            const unsigned* ep = (const unsigned*)(Bl + eb + 16 * mt + 4 * q);
            unsigned d0 = ep[0], d1 = ep[1];
            acc[mt].x *= __uint_as_float(d0 << 16);
            acc[mt].y *= __uint_as_float(d0 & 0xFFFF0000u);
            acc[mt].z *= __uint_as_float(d1 << 16);
            acc[mt].w *= __uint_as_float(d1 & 0xFFFF0000u);
        }

        // rare per-chunk reductions (wave-uniform branch)
        bool need_red = (it == steps - 1) || (!first && it == WARM - 1) ||
                        (lastc && it == steps - 2);
        if (need_red) {
            float zz = 0.f;
            #pragma unroll
            for (int mt = 0; mt < 8; ++mt)
                zz += (acc[mt].x + acc[mt].y) + (acc[mt].z + acc[mt].w);
            zz += __shfl_xor(zz, 16, 64);
            zz += __shfl_xor(zz, 32, 64);      // S-bar per batch, all q-lanes
            if (it == steps - 1) s_end = zz;
            else if (lastc && it == steps - 2) s_penult = zz;
            else s_pre = zz;
        }

        if (lastc && it == steps - 1) {
            // alpha_f = alpha-bar_{T-1} / (64 * S-bar_{T-2})
            float inv = 1.0f / (64.0f * s_penult);
            #pragma unroll
            for (int mt = 0; mt < 8; ++mt) {
                floatx4 o4;
                o4.x = acc[mt].x * inv; o4.y = acc[mt].y * inv;
                o4.z = acc[mt].z * inv; o4.w = acc[mt].w * inv;
                *(floatx4*)(out_alpha + (bg * 16 + n) * NS + 16 * mt + 4 * q) = o4;
            }
        }

        // pack to bf16 pairs: directly forms next step's B-fragments
        #pragma unroll
        for (int mt = 0; mt < 8; ++mt) {
            unsigned u0 = __float_as_uint(acc[mt].x) + 0x8000u;
            unsigned u1 = __float_as_uint(acc[mt].y) + 0x8000u;
            unsigned u2 = __float_as_uint(acc[mt].z) + 0x8000u;
            unsigned u3 = __float_as_uint(acc[mt].w) + 0x8000u;
            pk[2 * mt]     = __builtin_amdgcn_perm(u1, u0, 0x07060302u);
            pk[2 * mt + 1] = __builtin_amdgcn_perm(u3, u2, 0x07060302u);
        }
    }

    // chunk ll partial: telescoped  log(S_end) - log(S_pre) - CLEN*ln(64)
    if (q == 0) {
        float ll = __logf(s_end) - __logf(s_pre) - (float)CLEN * LN64;
        atomicAdd(&out_ll[bg * 16 + n], ll);
    }
}

extern "C" void kernel_launch(void* const* d_in, const int* in_sizes, int n_in,
                              void* d_out, int out_size, void* d_ws, size_t ws_size,
                              hipStream_t stream) {
    const float* x = (const float*)d_in[0];   // [B, T, EMIT] one-hot fp32
    const float* I = (const float*)d_in[1];   // [NS]
    const float* A = (const float*)d_in[2];   // [NS, NS]
    const float* B = (const float*)d_in[3];   // [EMIT, NS]
    float* out = (float*)d_out;               // alpha_f [B*NS] ++ loglik [B]

    zero_ll<<<1, BATCH, 0, stream>>>(out + BATCH * NS);
    hmm_scan<<<BG * NCHUNK, 64, 0, stream>>>(
        (const floatx4*)x, A, B, I, out, out + BATCH * NS);
}